// Round 6
// baseline (610.847 us; speedup 1.0000x reference)
//
#include <hip/hip_runtime.h>
#include <hip/hip_bf16.h>

#define C 128
#define NBMAX 256      // max coarse buckets (key >> 10)
#define EPB 16384      // entries per k_part2 block (8192 edges)

typedef __attribute__((ext_vector_type(8))) short bf16x8;
typedef __attribute__((ext_vector_type(4))) float f32x4;

__device__ __forceinline__ unsigned short f2bf(float f) {
    unsigned u = __builtin_bit_cast(unsigned, f);
    u += 0x7fff + ((u >> 16) & 1);          // RNE
    return (unsigned short)(u >> 16);
}
__device__ __forceinline__ float bflo(unsigned v) {
    return __builtin_bit_cast(float, v << 16);
}
__device__ __forceinline__ float bfhi(unsigned v) {
    return __builtin_bit_cast(float, v & 0xffff0000u);
}

// ---------------- k_emb: x_emb = x @ W1^T (bf16 out), mu = relu(x_emb) ------
__global__ __launch_bounds__(512) void k_emb(
    const float* __restrict__ x, const float* __restrict__ W1,
    unsigned short* __restrict__ x_emb, unsigned short* __restrict__ mu, int nN)
{
    __shared__ unsigned short Wl[C * C];   // bf16, XOR-swizzled 16B chunks
    const int t = threadIdx.x;
    for (int i = t; i < C * C / 8; i += 512) {
        int j = i >> 4, c = i & 15;
        const float* src = W1 + j * C + c * 8;
        float4 f0 = *(const float4*)src;
        float4 f1 = *(const float4*)(src + 4);
        alignas(16) unsigned short tmp[8] = {
            f2bf(f0.x), f2bf(f0.y), f2bf(f0.z), f2bf(f0.w),
            f2bf(f1.x), f2bf(f1.y), f2bf(f1.z), f2bf(f1.w)};
        int cs = c ^ (j & 7);
        *(uint4*)&Wl[j * C + cs * 8] = *(const uint4*)tmp;
    }
    __syncthreads();

    const int lane = t & 63, w = t >> 6;
    const int r0 = blockIdx.x * 128 + w * 16;
    if (r0 >= nN) return;
    const int lj = lane & 15, lk = lane >> 4;
    const int arow = r0 + lj;

    bf16x8 a[4];
    #pragma unroll
    for (int ks = 0; ks < 4; ++ks) {
        const float* ap = x + (size_t)arow * C + ks * 32 + lk * 8;
        float4 f0 = *(const float4*)ap;
        float4 f1 = *(const float4*)(ap + 4);
        alignas(16) unsigned short tmp[8] = {
            f2bf(f0.x), f2bf(f0.y), f2bf(f0.z), f2bf(f0.w),
            f2bf(f1.x), f2bf(f1.y), f2bf(f1.z), f2bf(f1.w)};
        a[ks] = *(const bf16x8*)tmp;
    }

    #pragma unroll
    for (int ct = 0; ct < 8; ++ct) {
        int j = ct * 16 + lj;
        f32x4 acc = {0.f, 0.f, 0.f, 0.f};
        #pragma unroll
        for (int ks = 0; ks < 4; ++ks) {
            int slot = (ks * 4 + lk) ^ (j & 7);
            bf16x8 b = *(const bf16x8*)&Wl[j * C + slot * 8];
            acc = __builtin_amdgcn_mfma_f32_16x16x32_bf16(a[ks], b, acc, 0, 0, 0);
        }
        #pragma unroll
        for (int r = 0; r < 4; ++r) {
            int row = r0 + lk * 4 + r;
            float v = acc[r];
            x_emb[(size_t)row * C + j] = f2bf(v);
            mu[(size_t)row * C + j]    = f2bf(fmaxf(v, 0.f));
        }
    }
}

// ---------------- k_mm2: t2 = mu @ W2^T, t3 = mu @ W3^T  (bf16 in/out) ------
__global__ __launch_bounds__(512) void k_mm2(
    const unsigned short* __restrict__ mu, const float* __restrict__ W2,
    const float* __restrict__ W3, unsigned short* __restrict__ t2,
    unsigned short* __restrict__ t3, int nN)
{
    __shared__ unsigned short Wl[2 * C * C];   // W2 then W3, swizzled
    const int t = threadIdx.x;
    for (int i = t; i < 2 * C * C / 8; i += 512) {
        int wsel = i >> 11, r = i & 2047;
        int j = r >> 4, c = r & 15;
        const float* src = (wsel ? W3 : W2) + j * C + c * 8;
        float4 f0 = *(const float4*)src;
        float4 f1 = *(const float4*)(src + 4);
        alignas(16) unsigned short tmp[8] = {
            f2bf(f0.x), f2bf(f0.y), f2bf(f0.z), f2bf(f0.w),
            f2bf(f1.x), f2bf(f1.y), f2bf(f1.z), f2bf(f1.w)};
        int cs = c ^ (j & 7);
        *(uint4*)&Wl[wsel * C * C + j * C + cs * 8] = *(const uint4*)tmp;
    }
    __syncthreads();

    const int lane = t & 63, w = t >> 6;
    const int r0 = blockIdx.x * 128 + w * 16;
    if (r0 >= nN) return;
    const int lj = lane & 15, lk = lane >> 4;
    const int arow = r0 + lj;

    bf16x8 a[4];
    #pragma unroll
    for (int ks = 0; ks < 4; ++ks)
        a[ks] = *(const bf16x8*)&mu[(size_t)arow * C + ks * 32 + lk * 8];

    #pragma unroll
    for (int ct = 0; ct < 8; ++ct) {
        int j = ct * 16 + lj;
        f32x4 acc2 = {0.f, 0.f, 0.f, 0.f};
        f32x4 acc3 = {0.f, 0.f, 0.f, 0.f};
        #pragma unroll
        for (int ks = 0; ks < 4; ++ks) {
            int slot = (ks * 4 + lk) ^ (j & 7);
            bf16x8 b2 = *(const bf16x8*)&Wl[j * C + slot * 8];
            bf16x8 b3 = *(const bf16x8*)&Wl[C * C + j * C + slot * 8];
            acc2 = __builtin_amdgcn_mfma_f32_16x16x32_bf16(a[ks], b2, acc2, 0, 0, 0);
            acc3 = __builtin_amdgcn_mfma_f32_16x16x32_bf16(a[ks], b3, acc3, 0, 0, 0);
        }
        #pragma unroll
        for (int r = 0; r < 4; ++r) {
            int row = r0 + lk * 4 + r;
            t2[(size_t)row * C + j] = f2bf(acc2[r]);
            t3[(size_t)row * C + j] = f2bf(acc3[r]);
        }
    }
}

// ---------------- degree count ----------------
__global__ void k_deg(const int* __restrict__ src, const int* __restrict__ dst,
                      int* __restrict__ deg, int nE, int nN)
{
    int e = blockIdx.x * 256 + threadIdx.x;
    if (e >= nE) return;
    atomicAdd(&deg[dst[e]], 1);
    atomicAdd(&deg[nN + src[e]], 1);
}

// ---------------- exclusive scan (3 kernels, chunk 512) ----------------
__global__ void k_scan1(const int* __restrict__ deg, int* __restrict__ off,
                        int* __restrict__ part, int n2)
{
    __shared__ int s[512];
    int t = threadIdx.x;
    int idx = blockIdx.x * 512 + t;
    int v = (idx < n2) ? deg[idx] : 0;
    s[t] = v;
    for (int o = 1; o < 512; o <<= 1) {
        __syncthreads();
        int x = (t >= o) ? s[t - o] : 0;
        __syncthreads();
        s[t] += x;
    }
    if (idx < n2) off[idx] = s[t] - v;
    if (t == 511) part[blockIdx.x] = s[511];
}

__global__ void k_scan2(int* __restrict__ part, int nb)
{
    __shared__ int s[512];
    int t = threadIdx.x;
    int v = (t < nb) ? part[t] : 0;
    s[t] = v;
    for (int o = 1; o < 512; o <<= 1) {
        __syncthreads();
        int x = (t >= o) ? s[t - o] : 0;
        __syncthreads();
        s[t] += x;
    }
    if (t < nb) part[t] = s[t] - v;
}

__global__ void k_scan3(int* __restrict__ off, const int* __restrict__ part, int n2)
{
    int idx = blockIdx.x * 256 + threadIdx.x;
    if (idx < n2) off[idx] += part[idx >> 9];
}

// ---------------- CSR build pass 1: block-local counting sort ---------------
__global__ __launch_bounds__(512) void k_part2(
    const int* __restrict__ src, const int* __restrict__ dst,
    const int* __restrict__ off, int* __restrict__ bcnt,
    unsigned* __restrict__ tmp, int nE, int nN, int n2)
{
    __shared__ unsigned sbuf[EPB];
    __shared__ unsigned char bid[EPB];
    __shared__ int hist[NBMAX], lstart[NBMAX], cur[NBMAX], gbase[NBMAX];

    const int t = threadIdx.x;
    const int e0 = blockIdx.x * (EPB / 2);
    const int e1 = min(e0 + EPB / 2, nE);

    for (int b = t; b < NBMAX; b += 512) { hist[b] = 0; cur[b] = 0; }
    __syncthreads();

    for (int e = e0 + t; e < e1; e += 512) {
        int s = src[e], d = dst[e];
        atomicAdd(&hist[d >> 10], 1);
        atomicAdd(&hist[(nN + s) >> 10], 1);
    }
    __syncthreads();

    for (int o = 1; o < NBMAX; o <<= 1) {
        int v = 0;
        if (t < NBMAX && t >= o) v = hist[t - o];
        __syncthreads();
        if (t < NBMAX) hist[t] += v;
        __syncthreads();
    }
    if (t < NBMAX) {
        int ls = (t == 0) ? 0 : hist[t - 1];
        lstart[t] = ls;
        int c = hist[t] - ls;
        if (c > 0)
            gbase[t] = off[t << 10] + atomicAdd(&bcnt[t * 16], c);
    }
    __syncthreads();

    for (int e = e0 + t; e < e1; e += 512) {
        int s = src[e], d = dst[e];
        {
            int key = d, b = key >> 10, krel = key & 1023;
            int pos = lstart[b] + atomicAdd(&cur[b], 1);
            sbuf[pos] = ((unsigned)krel << 17) | (unsigned)s;
            bid[pos] = (unsigned char)b;
        }
        {
            int key = nN + s, b = key >> 10, krel = key & 1023;
            int pos = lstart[b] + atomicAdd(&cur[b], 1);
            sbuf[pos] = ((unsigned)krel << 17) | (unsigned)d;
            bid[pos] = (unsigned char)b;
        }
    }
    __syncthreads();

    const int nent = 2 * (e1 - e0);
    for (int j = t; j < nent; j += 512) {
        int b = bid[j];
        tmp[gbase[b] + (j - lstart[b])] = sbuf[j];
    }
}

// ---------------- CSR build pass 2: per-bucket scatter ----------------------
__global__ __launch_bounds__(256) void k_place(
    const unsigned* __restrict__ tmp, const int* __restrict__ off,
    int* __restrict__ csr, int n2, int totE)
{
    __shared__ int lcnt[1024];
    const int key0 = blockIdx.x << 10;
    const int keyend = min(key0 + 1024, n2);
    const int s0 = off[key0];
    const int s1 = (keyend < n2) ? off[keyend] : totE;

    for (int i = threadIdx.x; i < 1024; i += 256) lcnt[i] = 0;
    __syncthreads();

    for (int i = s0 + threadIdx.x; i < s1; i += 256) {
        unsigned p = tmp[i];
        int krel = p >> 17;
        int val  = p & 0x1FFFF;
        int pos  = off[key0 + krel] + atomicAdd(&lcnt[krel], 1);
        csr[pos] = val;
    }
}

// ---------------- aggregation: merged in/out gather loops, MLP=16 ----------
// csr is padded by >=16 zero entries past 2*nE so unpredicated index loads
// are always in-bounds; out-of-list values are masked to 0.
template<int FINAL>
__global__ __launch_bounds__(256) void k_agg(
    const unsigned short* __restrict__ t2, const unsigned short* __restrict__ t3,
    const unsigned short* __restrict__ x_emb, unsigned short* __restrict__ mu_out,
    float* __restrict__ out,
    const int* __restrict__ csr, const int* __restrict__ off,
    const int* __restrict__ deg, int nN)
{
    const int lane = threadIdx.x & 63, w = threadIdx.x >> 6;
    const int lo = lane * 2;
    float sx = 0.f, sy = 0.f;
    for (int g = blockIdx.x * 4 + w; g < nN; g += gridDim.x * 4) {
        unsigned base = *(const unsigned*)&x_emb[(size_t)g * C + lo];
        float ax = bflo(base), ay = bfhi(base);
        float bx = 0.f, by = 0.f;
        float cx = 0.f, cy = 0.f;
        float dx = 0.f, dy = 0.f;

        const int o1 = off[g],      d1 = deg[g];
        const int o2 = off[nN + g], d2 = deg[nN + g];
        const int m = (d1 > d2) ? d1 : d2;

        for (int i = 0; i < m; i += 8) {
            #pragma unroll
            for (int j = 0; j < 8; ++j) {
                int k = i + j;
                // in-list -> t2
                int u2i = csr[o1 + k];
                unsigned v2 = *(const unsigned*)&t2[(size_t)u2i * C + lo];
                v2 = (k < d1) ? v2 : 0u;
                // out-list -> t3
                int u3i = csr[o2 + k];
                unsigned v3 = *(const unsigned*)&t3[(size_t)u3i * C + lo];
                v3 = (k < d2) ? v3 : 0u;
                if (j & 1) {
                    bx += bflo(v2); by += bfhi(v2);
                    dx += bflo(v3); dy += bfhi(v3);
                } else {
                    ax += bflo(v2); ay += bfhi(v2);
                    cx += bflo(v3); cy += bfhi(v3);
                }
            }
        }

        float rx = fmaxf((ax + bx) + (cx + dx), 0.f);
        float ry = fmaxf((ay + by) + (cy + dy), 0.f);
        if (FINAL) {
            sx += rx; sy += ry;
        } else {
            unsigned pk = ((unsigned)f2bf(ry) << 16) | (unsigned)f2bf(rx);
            *(unsigned*)&mu_out[(size_t)g * C + lo] = pk;
        }
    }
    if (FINAL) {
        __shared__ float red[512];
        red[threadIdx.x * 2]     = sx;
        red[threadIdx.x * 2 + 1] = sy;
        __syncthreads();
        if (w == 0) {
            float ax = red[lane * 2]         + red[(64 + lane) * 2] +
                       red[(128 + lane) * 2] + red[(192 + lane) * 2];
            float ay = red[lane * 2 + 1]         + red[(64 + lane) * 2 + 1] +
                       red[(128 + lane) * 2 + 1] + red[(192 + lane) * 2 + 1];
            atomicAdd(&out[lane * 2], ax);
            atomicAdd(&out[lane * 2 + 1], ay);
        }
    }
}

extern "C" void kernel_launch(void* const* d_in, const int* in_sizes, int n_in,
                              void* d_out, int out_size, void* d_ws, size_t ws_size,
                              hipStream_t stream)
{
    const float* x  = (const float*)d_in[0];
    const int*   ei = (const int*)d_in[1];
    const float* W1 = (const float*)d_in[2];
    const float* W2 = (const float*)d_in[3];
    const float* W3 = (const float*)d_in[4];
    float* out = (float*)d_out;

    const int nN = in_sizes[0] / C;
    const int nE = in_sizes[1] / 2;
    const int* src = ei;
    const int* dst = ei + nE;

    const size_t SZH = (size_t)nN * C * 2;   // bf16 node array
    char* p = (char*)d_ws;
    auto alloc = [&](size_t bytes) {
        char* r = p;
        p += (bytes + 511) & ~(size_t)511;
        return r;
    };
    unsigned short* x_emb = (unsigned short*)alloc(SZH);
    unsigned short* mu    = (unsigned short*)alloc(SZH);
    unsigned short* t2    = (unsigned short*)alloc(SZH);
    unsigned short* t3    = (unsigned short*)alloc(SZH);
    int* deg  = (int*)alloc((size_t)2 * nN * 4);
    int* off  = (int*)alloc((size_t)2 * nN * 4);
    int* part = (int*)alloc(512 * 4);
    int* bcnt = (int*)alloc((size_t)NBMAX * 16 * 4);
    unsigned* tmp = (unsigned*)alloc((size_t)2 * nE * 4);
    int* csr  = (int*)alloc((size_t)2 * nE * 4 + 64);   // +16 pad entries

    const int n2 = 2 * nN;
    const int nbuck = (n2 + 1023) >> 10;     // coarse buckets (<= NBMAX)

    hipMemsetAsync(deg, 0, (size_t)n2 * 4, stream);
    hipMemsetAsync(bcnt, 0, (size_t)NBMAX * 16 * 4, stream);
    hipMemsetAsync(csr + (size_t)2 * nE, 0, 64, stream);   // zero the pad
    hipMemsetAsync(out, 0, (size_t)out_size * 4, stream);

    const int mm_grid = (nN + 127) / 128;

    // iteration 1: mu = relu(x @ W1^T)
    k_emb<<<mm_grid, 512, 0, stream>>>(x, W1, x_emb, mu, nN);

    // CSR build
    k_deg<<<(nE + 255) / 256, 256, 0, stream>>>(src, dst, deg, nE, nN);
    const int nb = (n2 + 511) / 512;
    k_scan1<<<nb, 512, 0, stream>>>(deg, off, part, n2);
    k_scan2<<<1, 512, 0, stream>>>(part, nb);
    k_scan3<<<(n2 + 255) / 256, 256, 0, stream>>>(off, part, n2);
    const int npart = (nE + EPB / 2 - 1) / (EPB / 2);
    k_part2<<<npart, 512, 0, stream>>>(src, dst, off, bcnt, tmp, nE, nN, n2);
    k_place<<<nbuck, 256, 0, stream>>>(tmp, off, csr, n2, 2 * nE);

    // iteration 2
    k_mm2<<<mm_grid, 512, 0, stream>>>(mu, W2, W3, t2, t3, nN);
    k_agg<0><<<(nN + 3) / 4, 256, 0, stream>>>(t2, t3, x_emb, mu, out, csr, off, deg, nN);
    // iteration 3 (fused final reduce; mu never materialized)
    k_mm2<<<mm_grid, 512, 0, stream>>>(mu, W2, W3, t2, t3, nN);
    k_agg<1><<<2048, 256, 0, stream>>>(t2, t3, x_emb, nullptr, out, csr, off, deg, nN);
}

// Round 7
// 506.879 us; speedup vs baseline: 1.2051x; 1.2051x over previous
//
#include <hip/hip_runtime.h>
#include <hip/hip_bf16.h>

#define C 128
#define NBMAX 256      // max coarse buckets (key >> 10)
#define EPB 16384      // entries per k_part2 block (8192 edges)

typedef __attribute__((ext_vector_type(8))) short bf16x8;
typedef __attribute__((ext_vector_type(4))) float f32x4;

__device__ __forceinline__ unsigned short f2bf(float f) {
    unsigned u = __builtin_bit_cast(unsigned, f);
    u += 0x7fff + ((u >> 16) & 1);          // RNE
    return (unsigned short)(u >> 16);
}
__device__ __forceinline__ float bflo(unsigned v) {
    return __builtin_bit_cast(float, v << 16);
}
__device__ __forceinline__ float bfhi(unsigned v) {
    return __builtin_bit_cast(float, v & 0xffff0000u);
}
__device__ __forceinline__ float bf1(unsigned short v) {
    return __builtin_bit_cast(float, (unsigned)v << 16);
}

// ---------------- k_emb: x_emb = x @ W1^T (bf16 out), mu = relu(x_emb) ------
__global__ __launch_bounds__(512) void k_emb(
    const float* __restrict__ x, const float* __restrict__ W1,
    unsigned short* __restrict__ x_emb, unsigned short* __restrict__ mu, int nN)
{
    __shared__ unsigned short Wl[C * C];   // bf16, XOR-swizzled 16B chunks
    const int t = threadIdx.x;
    for (int i = t; i < C * C / 8; i += 512) {
        int j = i >> 4, c = i & 15;
        const float* src = W1 + j * C + c * 8;
        float4 f0 = *(const float4*)src;
        float4 f1 = *(const float4*)(src + 4);
        alignas(16) unsigned short tmp[8] = {
            f2bf(f0.x), f2bf(f0.y), f2bf(f0.z), f2bf(f0.w),
            f2bf(f1.x), f2bf(f1.y), f2bf(f1.z), f2bf(f1.w)};
        int cs = c ^ (j & 7);
        *(uint4*)&Wl[j * C + cs * 8] = *(const uint4*)tmp;
    }
    __syncthreads();

    const int lane = t & 63, w = t >> 6;
    const int r0 = blockIdx.x * 128 + w * 16;
    if (r0 >= nN) return;
    const int lj = lane & 15, lk = lane >> 4;
    const int arow = r0 + lj;

    bf16x8 a[4];
    #pragma unroll
    for (int ks = 0; ks < 4; ++ks) {
        const float* ap = x + (size_t)arow * C + ks * 32 + lk * 8;
        float4 f0 = *(const float4*)ap;
        float4 f1 = *(const float4*)(ap + 4);
        alignas(16) unsigned short tmp[8] = {
            f2bf(f0.x), f2bf(f0.y), f2bf(f0.z), f2bf(f0.w),
            f2bf(f1.x), f2bf(f1.y), f2bf(f1.z), f2bf(f1.w)};
        a[ks] = *(const bf16x8*)tmp;
    }

    #pragma unroll
    for (int ct = 0; ct < 8; ++ct) {
        int j = ct * 16 + lj;
        f32x4 acc = {0.f, 0.f, 0.f, 0.f};
        #pragma unroll
        for (int ks = 0; ks < 4; ++ks) {
            int slot = (ks * 4 + lk) ^ (j & 7);
            bf16x8 b = *(const bf16x8*)&Wl[j * C + slot * 8];
            acc = __builtin_amdgcn_mfma_f32_16x16x32_bf16(a[ks], b, acc, 0, 0, 0);
        }
        #pragma unroll
        for (int r = 0; r < 4; ++r) {
            int row = r0 + lk * 4 + r;
            float v = acc[r];
            x_emb[(size_t)row * C + j] = f2bf(v);
            mu[(size_t)row * C + j]    = f2bf(fmaxf(v, 0.f));
        }
    }
}

// ---- k_mm3: mu' = relu(x_emb + s_in @ W2^T + s_out @ W3^T)  (bf16) ---------
// FINAL=1: don't store mu'; column-reduce into out[128] via atomics.
template<int FINAL>
__global__ __launch_bounds__(512) void k_mm3(
    const unsigned short* __restrict__ s_in, const unsigned short* __restrict__ s_out,
    const float* __restrict__ W2, const float* __restrict__ W3,
    const unsigned short* __restrict__ x_emb,
    unsigned short* __restrict__ mu_out, float* __restrict__ out, int nN)
{
    __shared__ unsigned short Wl[2 * C * C];   // W2 then W3, swizzled
    __shared__ float redf[8 * C];              // FINAL column partials
    const int t = threadIdx.x;
    for (int i = t; i < 2 * C * C / 8; i += 512) {
        int wsel = i >> 11, r = i & 2047;
        int j = r >> 4, c = r & 15;
        const float* src = (wsel ? W3 : W2) + j * C + c * 8;
        float4 f0 = *(const float4*)src;
        float4 f1 = *(const float4*)(src + 4);
        alignas(16) unsigned short tmp[8] = {
            f2bf(f0.x), f2bf(f0.y), f2bf(f0.z), f2bf(f0.w),
            f2bf(f1.x), f2bf(f1.y), f2bf(f1.z), f2bf(f1.w)};
        int cs = c ^ (j & 7);
        *(uint4*)&Wl[wsel * C * C + j * C + cs * 8] = *(const uint4*)tmp;
    }
    if (FINAL) {
        for (int i = t; i < 8 * C; i += 512) redf[i] = 0.f;
    }
    __syncthreads();

    const int lane = t & 63, w = t >> 6;
    const int r0 = blockIdx.x * 128 + w * 16;
    const int lj = lane & 15, lk = lane >> 4;
    const bool active = (r0 < nN);

    if (active) {
        const int arow = r0 + lj;
        bf16x8 a2[4], a3[4];
        #pragma unroll
        for (int ks = 0; ks < 4; ++ks) {
            a2[ks] = *(const bf16x8*)&s_in [(size_t)arow * C + ks * 32 + lk * 8];
            a3[ks] = *(const bf16x8*)&s_out[(size_t)arow * C + ks * 32 + lk * 8];
        }

        #pragma unroll
        for (int ct = 0; ct < 8; ++ct) {
            int j = ct * 16 + lj;
            f32x4 acc = {0.f, 0.f, 0.f, 0.f};
            #pragma unroll
            for (int ks = 0; ks < 4; ++ks) {
                int slot = (ks * 4 + lk) ^ (j & 7);
                bf16x8 b2 = *(const bf16x8*)&Wl[j * C + slot * 8];
                bf16x8 b3 = *(const bf16x8*)&Wl[C * C + j * C + slot * 8];
                acc = __builtin_amdgcn_mfma_f32_16x16x32_bf16(a2[ks], b2, acc, 0, 0, 0);
                acc = __builtin_amdgcn_mfma_f32_16x16x32_bf16(a3[ks], b3, acc, 0, 0, 0);
            }
            float vsum = 0.f;
            #pragma unroll
            for (int r = 0; r < 4; ++r) {
                int row = r0 + lk * 4 + r;
                float v = acc[r] + bf1(x_emb[(size_t)row * C + j]);
                v = fmaxf(v, 0.f);
                if (FINAL) vsum += v;
                else mu_out[(size_t)row * C + j] = f2bf(v);
            }
            if (FINAL) {
                float s = vsum;
                s += __shfl_xor(s, 16);
                s += __shfl_xor(s, 32);
                if (lk == 0) redf[w * C + j] = s;
            }
        }
    }
    if (FINAL) {
        __syncthreads();
        if (t < C) {
            float acc = 0.f;
            #pragma unroll
            for (int ww = 0; ww < 8; ++ww) acc += redf[ww * C + t];
            atomicAdd(&out[t], acc);
        }
    }
}

// ---------------- degree count ----------------
__global__ void k_deg(const int* __restrict__ src, const int* __restrict__ dst,
                      int* __restrict__ deg, int nE, int nN)
{
    int e = blockIdx.x * 256 + threadIdx.x;
    if (e >= nE) return;
    atomicAdd(&deg[dst[e]], 1);
    atomicAdd(&deg[nN + src[e]], 1);
}

// ---------------- exclusive scan (3 kernels, chunk 512) ----------------
__global__ void k_scan1(const int* __restrict__ deg, int* __restrict__ off,
                        int* __restrict__ part, int n2)
{
    __shared__ int s[512];
    int t = threadIdx.x;
    int idx = blockIdx.x * 512 + t;
    int v = (idx < n2) ? deg[idx] : 0;
    s[t] = v;
    for (int o = 1; o < 512; o <<= 1) {
        __syncthreads();
        int x = (t >= o) ? s[t - o] : 0;
        __syncthreads();
        s[t] += x;
    }
    if (idx < n2) off[idx] = s[t] - v;
    if (t == 511) part[blockIdx.x] = s[511];
}

__global__ void k_scan2(int* __restrict__ part, int nb)
{
    __shared__ int s[512];
    int t = threadIdx.x;
    int v = (t < nb) ? part[t] : 0;
    s[t] = v;
    for (int o = 1; o < 512; o <<= 1) {
        __syncthreads();
        int x = (t >= o) ? s[t - o] : 0;
        __syncthreads();
        s[t] += x;
    }
    if (t < nb) part[t] = s[t] - v;
}

__global__ void k_scan3(int* __restrict__ off, const int* __restrict__ part, int n2)
{
    int idx = blockIdx.x * 256 + threadIdx.x;
    if (idx < n2) off[idx] += part[idx >> 9];
}

// ---------------- CSR build pass 1: block-local counting sort ---------------
__global__ __launch_bounds__(512) void k_part2(
    const int* __restrict__ src, const int* __restrict__ dst,
    const int* __restrict__ off, int* __restrict__ bcnt,
    unsigned* __restrict__ tmp, int nE, int nN, int n2)
{
    __shared__ unsigned sbuf[EPB];
    __shared__ unsigned char bid[EPB];
    __shared__ int hist[NBMAX], lstart[NBMAX], cur[NBMAX], gbase[NBMAX];

    const int t = threadIdx.x;
    const int e0 = blockIdx.x * (EPB / 2);
    const int e1 = min(e0 + EPB / 2, nE);

    for (int b = t; b < NBMAX; b += 512) { hist[b] = 0; cur[b] = 0; }
    __syncthreads();

    for (int e = e0 + t; e < e1; e += 512) {
        int s = src[e], d = dst[e];
        atomicAdd(&hist[d >> 10], 1);
        atomicAdd(&hist[(nN + s) >> 10], 1);
    }
    __syncthreads();

    for (int o = 1; o < NBMAX; o <<= 1) {
        int v = 0;
        if (t < NBMAX && t >= o) v = hist[t - o];
        __syncthreads();
        if (t < NBMAX) hist[t] += v;
        __syncthreads();
    }
    if (t < NBMAX) {
        int ls = (t == 0) ? 0 : hist[t - 1];
        lstart[t] = ls;
        int c = hist[t] - ls;
        if (c > 0)
            gbase[t] = off[t << 10] + atomicAdd(&bcnt[t * 16], c);
    }
    __syncthreads();

    for (int e = e0 + t; e < e1; e += 512) {
        int s = src[e], d = dst[e];
        {
            int key = d, b = key >> 10, krel = key & 1023;
            int pos = lstart[b] + atomicAdd(&cur[b], 1);
            sbuf[pos] = ((unsigned)krel << 17) | (unsigned)s;
            bid[pos] = (unsigned char)b;
        }
        {
            int key = nN + s, b = key >> 10, krel = key & 1023;
            int pos = lstart[b] + atomicAdd(&cur[b], 1);
            sbuf[pos] = ((unsigned)krel << 17) | (unsigned)d;
            bid[pos] = (unsigned char)b;
        }
    }
    __syncthreads();

    const int nent = 2 * (e1 - e0);
    for (int j = t; j < nent; j += 512) {
        int b = bid[j];
        tmp[gbase[b] + (j - lstart[b])] = sbuf[j];
    }
}

// ---------------- CSR build pass 2: per-bucket scatter ----------------------
__global__ __launch_bounds__(256) void k_place(
    const unsigned* __restrict__ tmp, const int* __restrict__ off,
    int* __restrict__ csr, int n2, int totE)
{
    __shared__ int lcnt[1024];
    const int key0 = blockIdx.x << 10;
    const int keyend = min(key0 + 1024, n2);
    const int s0 = off[key0];
    const int s1 = (keyend < n2) ? off[keyend] : totE;

    for (int i = threadIdx.x; i < 1024; i += 256) lcnt[i] = 0;
    __syncthreads();

    for (int i = s0 + threadIdx.x; i < s1; i += 256) {
        unsigned p = tmp[i];
        int krel = p >> 17;
        int val  = p & 0x1FFFF;
        int pos  = off[key0 + krel] + atomicAdd(&lcnt[krel], 1);
        csr[pos] = val;
    }
}

// ---- k_aggM: s_in[g] = sum(mu[in-nbrs]), s_out[g] = sum(mu[out-nbrs]) ------
// Merged loop, MLP=16; indices clamped WITHIN each list (clamped rows L1-hit),
// values masked to 0 past list end.
__global__ __launch_bounds__(256) void k_aggM(
    const unsigned short* __restrict__ mu,
    unsigned short* __restrict__ s_in, unsigned short* __restrict__ s_out,
    const int* __restrict__ csr, const int* __restrict__ off,
    const int* __restrict__ deg, int nN)
{
    const int lane = threadIdx.x & 63, w = threadIdx.x >> 6;
    const int lo = lane * 2;
    const int g = blockIdx.x * 4 + w;
    if (g >= nN) return;

    float ax = 0.f, ay = 0.f, bx = 0.f, by = 0.f;
    float cx = 0.f, cy = 0.f, dx = 0.f, dy = 0.f;

    const int o1 = off[g],      d1 = deg[g];
    const int o2 = off[nN + g], d2 = deg[nN + g];
    const int d1m = (d1 > 0) ? d1 - 1 : 0;
    const int d2m = (d2 > 0) ? d2 - 1 : 0;
    const int m = (d1 > d2) ? d1 : d2;

    for (int i = 0; i < m; i += 8) {
        #pragma unroll
        for (int j = 0; j < 8; ++j) {
            int k = i + j;
            int k1 = (k < d1m) ? k : d1m;          // clamp inside own list
            int u2 = csr[o1 + k1];
            unsigned v2 = *(const unsigned*)&mu[(size_t)u2 * C + lo];
            v2 = (k < d1) ? v2 : 0u;
            int k2 = (k < d2m) ? k : d2m;
            int u3 = csr[o2 + k2];
            unsigned v3 = *(const unsigned*)&mu[(size_t)u3 * C + lo];
            v3 = (k < d2) ? v3 : 0u;
            if (j & 1) {
                bx += bflo(v2); by += bfhi(v2);
                dx += bflo(v3); dy += bfhi(v3);
            } else {
                ax += bflo(v2); ay += bfhi(v2);
                cx += bflo(v3); cy += bfhi(v3);
            }
        }
    }

    float six = ax + bx, siy = ay + by;
    float sox = cx + dx, soy = cy + dy;
    *(unsigned*)&s_in [(size_t)g * C + lo] = ((unsigned)f2bf(siy) << 16) | (unsigned)f2bf(six);
    *(unsigned*)&s_out[(size_t)g * C + lo] = ((unsigned)f2bf(soy) << 16) | (unsigned)f2bf(sox);
}

extern "C" void kernel_launch(void* const* d_in, const int* in_sizes, int n_in,
                              void* d_out, int out_size, void* d_ws, size_t ws_size,
                              hipStream_t stream)
{
    const float* x  = (const float*)d_in[0];
    const int*   ei = (const int*)d_in[1];
    const float* W1 = (const float*)d_in[2];
    const float* W2 = (const float*)d_in[3];
    const float* W3 = (const float*)d_in[4];
    float* out = (float*)d_out;

    const int nN = in_sizes[0] / C;
    const int nE = in_sizes[1] / 2;
    const int* src = ei;
    const int* dst = ei + nE;

    const size_t SZH = (size_t)nN * C * 2;   // bf16 node array
    char* p = (char*)d_ws;
    auto alloc = [&](size_t bytes) {
        char* r = p;
        p += (bytes + 511) & ~(size_t)511;
        return r;
    };
    unsigned short* x_emb = (unsigned short*)alloc(SZH);
    unsigned short* mu    = (unsigned short*)alloc(SZH);
    unsigned short* s_in  = (unsigned short*)alloc(SZH);
    unsigned short* s_out = (unsigned short*)alloc(SZH);
    int* deg  = (int*)alloc((size_t)2 * nN * 4);
    int* off  = (int*)alloc((size_t)2 * nN * 4);
    int* part = (int*)alloc(512 * 4);
    int* bcnt = (int*)alloc((size_t)NBMAX * 16 * 4);
    unsigned* tmp = (unsigned*)alloc((size_t)2 * nE * 4);
    int* csr  = (int*)alloc((size_t)2 * nE * 4 + 64);   // +16 pad entries

    const int n2 = 2 * nN;
    const int nbuck = (n2 + 1023) >> 10;     // coarse buckets (<= NBMAX)

    hipMemsetAsync(deg, 0, (size_t)n2 * 4, stream);
    hipMemsetAsync(bcnt, 0, (size_t)NBMAX * 16 * 4, stream);
    hipMemsetAsync(csr + (size_t)2 * nE, 0, 64, stream);   // zero the pad
    hipMemsetAsync(out, 0, (size_t)out_size * 4, stream);

    const int mm_grid = (nN + 127) / 128;

    // iteration 1: mu = relu(x @ W1^T)
    k_emb<<<mm_grid, 512, 0, stream>>>(x, W1, x_emb, mu, nN);

    // CSR build
    k_deg<<<(nE + 255) / 256, 256, 0, stream>>>(src, dst, deg, nE, nN);
    const int nb = (n2 + 511) / 512;
    k_scan1<<<nb, 512, 0, stream>>>(deg, off, part, n2);
    k_scan2<<<1, 512, 0, stream>>>(part, nb);
    k_scan3<<<(n2 + 255) / 256, 256, 0, stream>>>(off, part, n2);
    const int npart = (nE + EPB / 2 - 1) / (EPB / 2);
    k_part2<<<npart, 512, 0, stream>>>(src, dst, off, bcnt, tmp, nE, nN, n2);
    k_place<<<nbuck, 256, 0, stream>>>(tmp, off, csr, n2, 2 * nE);

    // iteration 2: s = gather(mu1); mu2 = relu(x_emb + s_in@W2^T + s_out@W3^T)
    k_aggM<<<(nN + 3) / 4, 256, 0, stream>>>(mu, s_in, s_out, csr, off, deg, nN);
    k_mm3<0><<<mm_grid, 512, 0, stream>>>(s_in, s_out, W2, W3, x_emb, mu, out, nN);
    // iteration 3: s = gather(mu2); h_G = colsum(relu(...)) fused
    k_aggM<<<(nN + 3) / 4, 256, 0, stream>>>(mu, s_in, s_out, csr, off, deg, nN);
    k_mm3<1><<<mm_grid, 512, 0, stream>>>(s_in, s_out, W2, W3, x_emb, nullptr, out, nN);
}

// Round 8
// 396.358 us; speedup vs baseline: 1.5411x; 1.2788x over previous
//
#include <hip/hip_runtime.h>
#include <hip/hip_bf16.h>

#define C 128
#define NBMAX 256      // max coarse buckets (key >> 10)
#define EPB 16384      // entries per k_part2 block (8192 edges)

typedef __attribute__((ext_vector_type(8))) short bf16x8;
typedef __attribute__((ext_vector_type(4))) float f32x4;

__device__ __forceinline__ unsigned short f2bf(float f) {
    unsigned u = __builtin_bit_cast(unsigned, f);
    u += 0x7fff + ((u >> 16) & 1);          // RNE
    return (unsigned short)(u >> 16);
}
__device__ __forceinline__ float bflo(unsigned v) {
    return __builtin_bit_cast(float, v << 16);
}
__device__ __forceinline__ float bfhi(unsigned v) {
    return __builtin_bit_cast(float, v & 0xffff0000u);
}
__device__ __forceinline__ float bf1(unsigned short v) {
    return __builtin_bit_cast(float, (unsigned)v << 16);
}

// ---------------- k_emb: x_emb = x @ W1^T (bf16 out), mu = relu(x_emb) ------
__global__ __launch_bounds__(512) void k_emb(
    const float* __restrict__ x, const float* __restrict__ W1,
    unsigned short* __restrict__ x_emb, unsigned short* __restrict__ mu, int nN)
{
    __shared__ unsigned short Wl[C * C];   // bf16, XOR-swizzled 16B chunks
    const int t = threadIdx.x;
    for (int i = t; i < C * C / 8; i += 512) {
        int j = i >> 4, c = i & 15;
        const float* src = W1 + j * C + c * 8;
        float4 f0 = *(const float4*)src;
        float4 f1 = *(const float4*)(src + 4);
        alignas(16) unsigned short tmp[8] = {
            f2bf(f0.x), f2bf(f0.y), f2bf(f0.z), f2bf(f0.w),
            f2bf(f1.x), f2bf(f1.y), f2bf(f1.z), f2bf(f1.w)};
        int cs = c ^ (j & 7);
        *(uint4*)&Wl[j * C + cs * 8] = *(const uint4*)tmp;
    }
    __syncthreads();

    const int lane = t & 63, w = t >> 6;
    const int r0 = blockIdx.x * 128 + w * 16;
    if (r0 >= nN) return;
    const int lj = lane & 15, lk = lane >> 4;
    const int arow = r0 + lj;

    bf16x8 a[4];
    #pragma unroll
    for (int ks = 0; ks < 4; ++ks) {
        const float* ap = x + (size_t)arow * C + ks * 32 + lk * 8;
        float4 f0 = *(const float4*)ap;
        float4 f1 = *(const float4*)(ap + 4);
        alignas(16) unsigned short tmp[8] = {
            f2bf(f0.x), f2bf(f0.y), f2bf(f0.z), f2bf(f0.w),
            f2bf(f1.x), f2bf(f1.y), f2bf(f1.z), f2bf(f1.w)};
        a[ks] = *(const bf16x8*)tmp;
    }

    #pragma unroll
    for (int ct = 0; ct < 8; ++ct) {
        int j = ct * 16 + lj;
        f32x4 acc = {0.f, 0.f, 0.f, 0.f};
        #pragma unroll
        for (int ks = 0; ks < 4; ++ks) {
            int slot = (ks * 4 + lk) ^ (j & 7);
            bf16x8 b = *(const bf16x8*)&Wl[j * C + slot * 8];
            acc = __builtin_amdgcn_mfma_f32_16x16x32_bf16(a[ks], b, acc, 0, 0, 0);
        }
        #pragma unroll
        for (int r = 0; r < 4; ++r) {
            int row = r0 + lk * 4 + r;
            float v = acc[r];
            x_emb[(size_t)row * C + j] = f2bf(v);
            mu[(size_t)row * C + j]    = f2bf(fmaxf(v, 0.f));
        }
    }
}

// ---- k_mm3: mu' = relu(x_emb + s_in @ W2^T + s_out @ W3^T)  (bf16) ---------
// FINAL=1: don't store mu'; column-reduce into out[128] via atomics.
template<int FINAL>
__global__ __launch_bounds__(512) void k_mm3(
    const unsigned short* __restrict__ s_in, const unsigned short* __restrict__ s_out,
    const float* __restrict__ W2, const float* __restrict__ W3,
    const unsigned short* __restrict__ x_emb,
    unsigned short* __restrict__ mu_out, float* __restrict__ out, int nN)
{
    __shared__ unsigned short Wl[2 * C * C];   // W2 then W3, swizzled
    __shared__ float redf[8 * C];              // FINAL column partials
    const int t = threadIdx.x;
    for (int i = t; i < 2 * C * C / 8; i += 512) {
        int wsel = i >> 11, r = i & 2047;
        int j = r >> 4, c = r & 15;
        const float* src = (wsel ? W3 : W2) + j * C + c * 8;
        float4 f0 = *(const float4*)src;
        float4 f1 = *(const float4*)(src + 4);
        alignas(16) unsigned short tmp[8] = {
            f2bf(f0.x), f2bf(f0.y), f2bf(f0.z), f2bf(f0.w),
            f2bf(f1.x), f2bf(f1.y), f2bf(f1.z), f2bf(f1.w)};
        int cs = c ^ (j & 7);
        *(uint4*)&Wl[wsel * C * C + j * C + cs * 8] = *(const uint4*)tmp;
    }
    if (FINAL) {
        for (int i = t; i < 8 * C; i += 512) redf[i] = 0.f;
    }
    __syncthreads();

    const int lane = t & 63, w = t >> 6;
    const int r0 = blockIdx.x * 128 + w * 16;
    const int lj = lane & 15, lk = lane >> 4;
    const bool active = (r0 < nN);

    if (active) {
        const int arow = r0 + lj;
        bf16x8 a2[4], a3[4];
        #pragma unroll
        for (int ks = 0; ks < 4; ++ks) {
            a2[ks] = *(const bf16x8*)&s_in [(size_t)arow * C + ks * 32 + lk * 8];
            a3[ks] = *(const bf16x8*)&s_out[(size_t)arow * C + ks * 32 + lk * 8];
        }

        #pragma unroll
        for (int ct = 0; ct < 8; ++ct) {
            int j = ct * 16 + lj;
            f32x4 acc = {0.f, 0.f, 0.f, 0.f};
            #pragma unroll
            for (int ks = 0; ks < 4; ++ks) {
                int slot = (ks * 4 + lk) ^ (j & 7);
                bf16x8 b2 = *(const bf16x8*)&Wl[j * C + slot * 8];
                bf16x8 b3 = *(const bf16x8*)&Wl[C * C + j * C + slot * 8];
                acc = __builtin_amdgcn_mfma_f32_16x16x32_bf16(a2[ks], b2, acc, 0, 0, 0);
                acc = __builtin_amdgcn_mfma_f32_16x16x32_bf16(a3[ks], b3, acc, 0, 0, 0);
            }
            float vsum = 0.f;
            #pragma unroll
            for (int r = 0; r < 4; ++r) {
                int row = r0 + lk * 4 + r;
                float v = acc[r] + bf1(x_emb[(size_t)row * C + j]);
                v = fmaxf(v, 0.f);
                if (FINAL) vsum += v;
                else mu_out[(size_t)row * C + j] = f2bf(v);
            }
            if (FINAL) {
                float s = vsum;
                s += __shfl_xor(s, 16);
                s += __shfl_xor(s, 32);
                if (lk == 0) redf[w * C + j] = s;
            }
        }
    }
    if (FINAL) {
        __syncthreads();
        if (t < C) {
            float acc = 0.f;
            #pragma unroll
            for (int ww = 0; ww < 8; ++ww) acc += redf[ww * C + t];
            atomicAdd(&out[t], acc);
        }
    }
}

// ---------------- coarse bucket histogram (replaces k_deg) ------------------
// One LDS histogram per block, one global atomic per block per bucket.
__global__ __launch_bounds__(512) void k_hist(
    const int* __restrict__ src, const int* __restrict__ dst,
    int* __restrict__ bkt, int nE, int nN)
{
    __shared__ int h[NBMAX];
    const int t = threadIdx.x;
    for (int i = t; i < NBMAX; i += 512) h[i] = 0;
    __syncthreads();

    const int e0 = blockIdx.x * (EPB / 2);
    const int e1 = min(e0 + EPB / 2, nE);
    for (int e = e0 + t; e < e1; e += 512) {
        int s = src[e], d = dst[e];
        atomicAdd(&h[d >> 10], 1);
        atomicAdd(&h[(nN + s) >> 10], 1);
    }
    __syncthreads();
    for (int i = t; i < NBMAX; i += 512)
        if (h[i]) atomicAdd(&bkt[i], h[i]);
}

// ---------------- bucket-base scan: obk[0..NBMAX] = exclusive scan ----------
__global__ __launch_bounds__(512) void k_scanB(
    const int* __restrict__ bkt, int* __restrict__ obk)
{
    __shared__ int s[NBMAX];
    const int t = threadIdx.x;
    if (t < NBMAX) s[t] = bkt[t];
    for (int o = 1; o < NBMAX; o <<= 1) {
        __syncthreads();
        int v = (t < NBMAX && t >= o) ? s[t - o] : 0;
        __syncthreads();
        if (t < NBMAX) s[t] += v;
    }
    __syncthreads();
    if (t < NBMAX) obk[t + 1] = s[t];
    if (t == 0) obk[0] = 0;
}

// ---------------- CSR build pass 1: block-local counting sort ---------------
__global__ __launch_bounds__(512) void k_part2(
    const int* __restrict__ src, const int* __restrict__ dst,
    const int* __restrict__ obk, int* __restrict__ bcnt,
    unsigned* __restrict__ tmp, int nE, int nN, int n2)
{
    __shared__ unsigned sbuf[EPB];
    __shared__ unsigned char bid[EPB];
    __shared__ int hist[NBMAX], lstart[NBMAX], cur[NBMAX], gbase[NBMAX];

    const int t = threadIdx.x;
    const int e0 = blockIdx.x * (EPB / 2);
    const int e1 = min(e0 + EPB / 2, nE);

    for (int b = t; b < NBMAX; b += 512) { hist[b] = 0; cur[b] = 0; }
    __syncthreads();

    for (int e = e0 + t; e < e1; e += 512) {
        int s = src[e], d = dst[e];
        atomicAdd(&hist[d >> 10], 1);
        atomicAdd(&hist[(nN + s) >> 10], 1);
    }
    __syncthreads();

    for (int o = 1; o < NBMAX; o <<= 1) {
        int v = 0;
        if (t < NBMAX && t >= o) v = hist[t - o];
        __syncthreads();
        if (t < NBMAX) hist[t] += v;
        __syncthreads();
    }
    if (t < NBMAX) {
        int ls = (t == 0) ? 0 : hist[t - 1];
        lstart[t] = ls;
        int c = hist[t] - ls;
        if (c > 0)
            gbase[t] = obk[t] + atomicAdd(&bcnt[t * 16], c);
    }
    __syncthreads();

    for (int e = e0 + t; e < e1; e += 512) {
        int s = src[e], d = dst[e];
        {
            int key = d, b = key >> 10, krel = key & 1023;
            int pos = lstart[b] + atomicAdd(&cur[b], 1);
            sbuf[pos] = ((unsigned)krel << 17) | (unsigned)s;
            bid[pos] = (unsigned char)b;
        }
        {
            int key = nN + s, b = key >> 10, krel = key & 1023;
            int pos = lstart[b] + atomicAdd(&cur[b], 1);
            sbuf[pos] = ((unsigned)krel << 17) | (unsigned)d;
            bid[pos] = (unsigned char)b;
        }
    }
    __syncthreads();

    const int nent = 2 * (e1 - e0);
    for (int j = t; j < nent; j += 512) {
        int b = bid[j];
        tmp[gbase[b] + (j - lstart[b])] = sbuf[j];
    }
}

// ---------------- CSR build pass 2: per-key offsets + scatter ---------------
// Per bucket (1024 keys): LDS per-key histogram of the bucket's tmp span,
// LDS scan -> off[] & deg[] (coalesced writes), then in-span scatter to csr.
__global__ __launch_bounds__(256) void k_place2(
    const unsigned* __restrict__ tmp, const int* __restrict__ obk,
    int* __restrict__ off, int* __restrict__ deg, int* __restrict__ csr, int n2)
{
    __shared__ int cnt[1024], excl[1024], part[256];
    const int t = threadIdx.x;
    const int b = blockIdx.x;
    const int key0 = b << 10;
    const int s0 = obk[b];
    const int s1 = obk[b + 1];

    for (int i = t; i < 1024; i += 256) cnt[i] = 0;
    __syncthreads();

    for (int i = s0 + t; i < s1; i += 256)
        atomicAdd(&cnt[tmp[i] >> 17], 1);
    __syncthreads();

    // scan 1024 with 256 threads: serial-4 + Hillis-Steele over partials
    const int base = t * 4;
    int c0 = cnt[base], c1 = cnt[base + 1], c2 = cnt[base + 2], c3 = cnt[base + 3];
    int s = c0 + c1 + c2 + c3;
    part[t] = s;
    for (int o = 1; o < 256; o <<= 1) {
        __syncthreads();
        int v = (t >= o) ? part[t - o] : 0;
        __syncthreads();
        part[t] += v;
    }
    __syncthreads();
    int pb = part[t] - s;                 // exclusive prefix of this group
    excl[base]     = pb;
    excl[base + 1] = pb + c0;
    excl[base + 2] = pb + c0 + c1;
    excl[base + 3] = pb + c0 + c1 + c2;
    __syncthreads();

    // write global off/deg (coalesced)
    for (int i = t; i < 1024; i += 256) {
        int key = key0 + i;
        if (key < n2) {
            off[key] = s0 + excl[i];
            deg[key] = cnt[i];
        }
    }
    __syncthreads();
    for (int i = t; i < 1024; i += 256) cnt[i] = 0;   // reuse as cursors
    __syncthreads();

    for (int i = s0 + t; i < s1; i += 256) {
        unsigned p = tmp[i];
        int krel = p >> 17;
        int val  = p & 0x1FFFF;
        int pos  = s0 + excl[krel] + atomicAdd(&cnt[krel], 1);
        csr[pos] = val;
    }
}

// ---- k_aggM: s_in[g] = sum(mu[in-nbrs]), s_out[g] = sum(mu[out-nbrs]) ------
__global__ __launch_bounds__(256) void k_aggM(
    const unsigned short* __restrict__ mu,
    unsigned short* __restrict__ s_in, unsigned short* __restrict__ s_out,
    const int* __restrict__ csr, const int* __restrict__ off,
    const int* __restrict__ deg, int nN)
{
    const int lane = threadIdx.x & 63, w = threadIdx.x >> 6;
    const int lo = lane * 2;
    const int g = blockIdx.x * 4 + w;
    if (g >= nN) return;

    float ax = 0.f, ay = 0.f, bx = 0.f, by = 0.f;
    float cx = 0.f, cy = 0.f, dx = 0.f, dy = 0.f;

    const int o1 = off[g],      d1 = deg[g];
    const int o2 = off[nN + g], d2 = deg[nN + g];
    const int d1m = (d1 > 0) ? d1 - 1 : 0;
    const int d2m = (d2 > 0) ? d2 - 1 : 0;
    const int m = (d1 > d2) ? d1 : d2;

    for (int i = 0; i < m; i += 8) {
        #pragma unroll
        for (int j = 0; j < 8; ++j) {
            int k = i + j;
            int k1 = (k < d1m) ? k : d1m;          // clamp inside own list
            int u2 = csr[o1 + k1];
            unsigned v2 = *(const unsigned*)&mu[(size_t)u2 * C + lo];
            v2 = (k < d1) ? v2 : 0u;
            int k2 = (k < d2m) ? k : d2m;
            int u3 = csr[o2 + k2];
            unsigned v3 = *(const unsigned*)&mu[(size_t)u3 * C + lo];
            v3 = (k < d2) ? v3 : 0u;
            if (j & 1) {
                bx += bflo(v2); by += bfhi(v2);
                dx += bflo(v3); dy += bfhi(v3);
            } else {
                ax += bflo(v2); ay += bfhi(v2);
                cx += bflo(v3); cy += bfhi(v3);
            }
        }
    }

    float six = ax + bx, siy = ay + by;
    float sox = cx + dx, soy = cy + dy;
    *(unsigned*)&s_in [(size_t)g * C + lo] = ((unsigned)f2bf(siy) << 16) | (unsigned)f2bf(six);
    *(unsigned*)&s_out[(size_t)g * C + lo] = ((unsigned)f2bf(soy) << 16) | (unsigned)f2bf(sox);
}

extern "C" void kernel_launch(void* const* d_in, const int* in_sizes, int n_in,
                              void* d_out, int out_size, void* d_ws, size_t ws_size,
                              hipStream_t stream)
{
    const float* x  = (const float*)d_in[0];
    const int*   ei = (const int*)d_in[1];
    const float* W1 = (const float*)d_in[2];
    const float* W2 = (const float*)d_in[3];
    const float* W3 = (const float*)d_in[4];
    float* out = (float*)d_out;

    const int nN = in_sizes[0] / C;
    const int nE = in_sizes[1] / 2;
    const int* src = ei;
    const int* dst = ei + nE;

    const size_t SZH = (size_t)nN * C * 2;   // bf16 node array
    char* p = (char*)d_ws;
    auto alloc = [&](size_t bytes) {
        char* r = p;
        p += (bytes + 511) & ~(size_t)511;
        return r;
    };
    unsigned short* x_emb = (unsigned short*)alloc(SZH);
    unsigned short* mu    = (unsigned short*)alloc(SZH);
    unsigned short* s_in  = (unsigned short*)alloc(SZH);
    unsigned short* s_out = (unsigned short*)alloc(SZH);
    int* deg  = (int*)alloc((size_t)2 * nN * 4);
    int* off  = (int*)alloc((size_t)2 * nN * 4);
    int* bkt  = (int*)alloc(NBMAX * 4);
    int* obk  = (int*)alloc((NBMAX + 1) * 4);
    int* bcnt = (int*)alloc((size_t)NBMAX * 16 * 4);
    unsigned* tmp = (unsigned*)alloc((size_t)2 * nE * 4);
    int* csr  = (int*)alloc((size_t)2 * nE * 4 + 64);   // +16 pad entries

    const int n2 = 2 * nN;
    const int nbuck = (n2 + 1023) >> 10;     // coarse buckets (<= NBMAX)

    hipMemsetAsync(bkt, 0, NBMAX * 4, stream);
    hipMemsetAsync(bcnt, 0, (size_t)NBMAX * 16 * 4, stream);
    hipMemsetAsync(csr + (size_t)2 * nE, 0, 64, stream);   // zero the pad
    hipMemsetAsync(out, 0, (size_t)out_size * 4, stream);

    const int mm_grid = (nN + 127) / 128;
    const int npart = (nE + EPB / 2 - 1) / (EPB / 2);

    // iteration 1: mu = relu(x @ W1^T)
    k_emb<<<mm_grid, 512, 0, stream>>>(x, W1, x_emb, mu, nN);

    // CSR build (no per-key atomics anywhere)
    k_hist<<<npart, 512, 0, stream>>>(src, dst, bkt, nE, nN);
    k_scanB<<<1, 512, 0, stream>>>(bkt, obk);
    k_part2<<<npart, 512, 0, stream>>>(src, dst, obk, bcnt, tmp, nE, nN, n2);
    k_place2<<<nbuck, 256, 0, stream>>>(tmp, obk, off, deg, csr, n2);

    // iteration 2: s = gather(mu1); mu2 = relu(x_emb + s_in@W2^T + s_out@W3^T)
    k_aggM<<<(nN + 3) / 4, 256, 0, stream>>>(mu, s_in, s_out, csr, off, deg, nN);
    k_mm3<0><<<mm_grid, 512, 0, stream>>>(s_in, s_out, W2, W3, x_emb, mu, out, nN);
    // iteration 3: s = gather(mu2); h_G = colsum(relu(...)) fused
    k_aggM<<<(nN + 3) / 4, 256, 0, stream>>>(mu, s_in, s_out, csr, off, deg, nN);
    k_mm3<1><<<mm_grid, 512, 0, stream>>>(s_in, s_out, W2, W3, x_emb, nullptr, out, nN);
}